// Round 10
// baseline (456.249 us; speedup 1.0000x reference)
//
#include <hip/hip_runtime.h>

typedef __attribute__((ext_vector_type(8))) short bf16x8;
typedef __attribute__((ext_vector_type(4))) float f32x4;

#define MFMA_BF16(a, b, c) __builtin_amdgcn_mfma_f32_16x16x32_bf16((a), (b), (c), 0, 0, 0)

__device__ __forceinline__ unsigned short bf16rn(float f) {
  unsigned u = __builtin_bit_cast(unsigned, f);
  u += 0x7fffu + ((u >> 16) & 1u);
  return (unsigned short)(u >> 16);
}

__device__ __forceinline__ void gld_lds16(const void* g, void* l) {
  __builtin_amdgcn_global_load_lds((const __attribute__((address_space(1))) void*)g,
                                   (__attribute__((address_space(3))) void*)l, 16, 0, 0);
}

// ---------------- weight convert + transpose: W[K][N] f32 -> W^T[N][K] bf16 ----------------
__global__ __launch_bounds__(256) void convT_kernel(
    const float* __restrict__ wq, const float* __restrict__ wk,
    const float* __restrict__ wv, const float* __restrict__ wo,
    const float* __restrict__ wfc, const float* __restrict__ wpj,
    unsigned short* __restrict__ wsb)
{
  const int bid = blockIdx.x;
  const float* src; unsigned short* dst; int K, N, lb;
  if (bid < 1024) {
    const int m = bid >> 8; lb = bid & 255; K = 1024; N = 1024;
    src = (m == 0) ? wq : (m == 1) ? wk : (m == 2) ? wv : wo;
    dst = wsb + (size_t)m * 1048576u;
  } else if (bid < 2048) {
    lb = bid - 1024; K = 1024; N = 4096; src = wfc; dst = wsb + 4194304u;
  } else {
    lb = bid - 2048; K = 4096; N = 1024; src = wpj; dst = wsb + 8388608u;
  }
  const int tiles_k = K >> 6;
  const int tk = lb % tiles_k, tn = lb / tiles_k;
  const int k0 = tk << 6, n0 = tn << 6;
  const int t = threadIdx.x, kq = t & 15, nq = t >> 4;
  float4 r[4];
#pragma unroll
  for (int i = 0; i < 4; ++i)
    r[i] = *(const float4*)(src + (size_t)(k0 + kq * 4 + i) * N + n0 + nq * 4);
#pragma unroll
  for (int j = 0; j < 4; ++j) {
    ushort4 o;
    o.x = bf16rn(((const float*)&r[0])[j]);
    o.y = bf16rn(((const float*)&r[1])[j]);
    o.z = bf16rn(((const float*)&r[2])[j]);
    o.w = bf16rn(((const float*)&r[3])[j]);
    *(ushort4*)(dst + (size_t)(n0 + nq * 4 + j) * K + k0 + kq * 4) = o;
  }
}

// ---------------- layernorm: f32 [rows][1024] -> bf16 ----------------
__global__ __launch_bounds__(256) void ln_kernel(
    const float* __restrict__ x, const float* __restrict__ sc,
    const float* __restrict__ sh, unsigned short* __restrict__ out)
{
  const int row = blockIdx.x, t = threadIdx.x;
  const float4 v = *(const float4*)(x + (size_t)row * 1024 + t * 4);
  float s = v.x + v.y + v.z + v.w;
  float q = v.x * v.x + v.y * v.y + v.z * v.z + v.w * v.w;
#pragma unroll
  for (int off = 1; off < 64; off <<= 1) { s += __shfl_xor(s, off); q += __shfl_xor(q, off); }
  __shared__ float ps[4], pq[4];
  if ((t & 63) == 0) { ps[t >> 6] = s; pq[t >> 6] = q; }
  __syncthreads();
  s = ps[0] + ps[1] + ps[2] + ps[3];
  q = pq[0] + pq[1] + pq[2] + pq[3];
  const float mean = s * (1.f / 1024.f);
  const float var = q * (1.f / 1024.f) - mean * mean;
  const float inv = rsqrtf(var + 1e-5f);
  const float4 scv = *(const float4*)(sc + t * 4);
  const float4 shv = *(const float4*)(sh + t * 4);
  ushort4 o;
  o.x = bf16rn((v.x - mean) * inv * scv.x + shv.x);
  o.y = bf16rn((v.y - mean) * inv * scv.y + shv.y);
  o.z = bf16rn((v.z - mean) * inv * scv.z + shv.z);
  o.w = bf16rn((v.w - mean) * inv * scv.w + shv.w);
  *(ushort4*)(out + (size_t)row * 1024 + t * 4) = o;
}

// ---------------- 128x128 BK=32 GEMM (m97 structure): multi-block overlap + swizzle ------
// 16KB LDS (EPI!=1) -> several blocks/CU; cross-block wave overlap hides barrier/LDS
// latency (m114). LDS rows 64B; content slot' = slot ^ (row&3) ^ ((row>>2)&3) (applied on
// stage SOURCE col and frag reads) -> ds_read_b128 is 2-way (free). Stage stays coalesced.
// XCD tm-stripes: tm = (bid&7)*8 + (j&7), tn = j>>3 (grid = 64 * nTn, M fixed 8192).
// EPI: 0 bf16; 1 bf16 transposed into v_T[b*1024+n][s]; 2 f32 = acc+bias+resid;
//      3 bf16 = gelu(acc+bias)
template<int EPI>
__global__ __launch_bounds__(256) void gemm_bt(
    const unsigned short* __restrict__ A, const unsigned short* __restrict__ Bt,
    int M, int N, int K,
    unsigned short* __restrict__ outb, float* __restrict__ outf,
    const float* __restrict__ bias, const float* __restrict__ resid)
{
  __shared__ char smem[(EPI == 1) ? 36864 : 16384];
  const int t = threadIdx.x;
  const int lane = t & 63, w = t >> 6;
  const int g = lane >> 4, l15 = lane & 15;
  const int wr = w >> 1, wc = w & 1;
  const int bid = blockIdx.x;
  const int j = bid >> 3;
  const int tm = (bid & 7) * 8 + (j & 7);
  const int tn = j >> 3;
  const int m0 = tm * 128, n0 = tn * 128;

  f32x4 acc[4][4] = {};

  // stage: c = it*256+t covers row c>>2, slot c&3; source col swizzled (it-independent)
  const int ce = (((t & 3) ^ ((t >> 2) & 3) ^ ((t >> 4) & 3)) << 3);  // element offset
  const int rbase = t >> 2;  // + it*64
  // frag-read slot byte offset (lane-constant)
  const int slt = ((g ^ (l15 & 3) ^ ((l15 >> 2) & 3)) << 4);

  const int nkt = K >> 5;
  for (int kt = 0; kt < nkt; ++kt) {
    const int k0 = kt << 5;
    __syncthreads();
#pragma unroll
    for (int it = 0; it < 2; ++it) {
      const int row = it * 64 + rbase;
      gld_lds16(A + (size_t)(m0 + row) * K + k0 + ce,
                smem + ((it * 256 + w * 64) << 4));
      gld_lds16(Bt + (size_t)(n0 + row) * K + k0 + ce,
                smem + 8192 + ((it * 256 + w * 64) << 4));
    }
    __syncthreads();  // drains vmcnt(0): staged data visible
    bf16x8 a[4], b[4];
#pragma unroll
    for (int mi = 0; mi < 4; ++mi)
      a[mi] = *(const bf16x8*)(smem + (wr * 64 + mi * 16 + l15) * 64 + slt);
#pragma unroll
    for (int ni = 0; ni < 4; ++ni)
      b[ni] = *(const bf16x8*)(smem + 8192 + (wc * 64 + ni * 16 + l15) * 64 + slt);
#pragma unroll
    for (int mi = 0; mi < 4; ++mi)
#pragma unroll
      for (int ni = 0; ni < 4; ++ni)
        acc[mi][ni] = MFMA_BF16(a[mi], b[ni], acc[mi][ni]);
  }

  if constexpr (EPI == 0 || EPI == 3) {
#pragma unroll
    for (int mi = 0; mi < 4; ++mi)
#pragma unroll
      for (int ni = 0; ni < 4; ++ni) {
        const int n = n0 + wc * 64 + ni * 16 + l15;
        float bn = 0.f;
        if constexpr (EPI == 3) bn = bias[n];
#pragma unroll
        for (int r = 0; r < 4; ++r) {
          const int m = m0 + wr * 64 + mi * 16 + 4 * g + r;
          float v = acc[mi][ni][r];
          if constexpr (EPI == 3) {
            v += bn;
            const float u = v;
            const float inner = 0.7978845608028654f * (u + 0.044715f * u * u * u);
            v = 0.5f * u * (1.0f + tanhf(inner));
          }
          outb[(size_t)m * N + n] = bf16rn(v);
        }
      }
  } else if constexpr (EPI == 2) {
#pragma unroll
    for (int mi = 0; mi < 4; ++mi)
#pragma unroll
      for (int ni = 0; ni < 4; ++ni) {
        const int n = n0 + wc * 64 + ni * 16 + l15;
        const float bn = bias[n];
#pragma unroll
        for (int r = 0; r < 4; ++r) {
          const int m = m0 + wr * 64 + mi * 16 + 4 * g + r;
          outf[(size_t)m * N + n] = acc[mi][ni][r] + bn + resid[(size_t)m * N + n];
        }
      }
  } else {  // EPI == 1: transposed store for V
    __syncthreads();
    unsigned short* T = (unsigned short*)(smem + w * 9216);  // [64 n][72 m-padded]
#pragma unroll
    for (int mi = 0; mi < 4; ++mi)
#pragma unroll
      for (int ni = 0; ni < 4; ++ni)
#pragma unroll
        for (int r = 0; r < 4; ++r)
          T[(ni * 16 + l15) * 72 + mi * 16 + 4 * g + r] = bf16rn(acc[mi][ni][r]);
    asm volatile("s_waitcnt lgkmcnt(0)" ::: "memory");
    const int bidx = m0 >> 11;
    const int srow = (m0 & 2047) + wr * 64 + ((lane & 7) << 3);
#pragma unroll
    for (int rr = 0; rr < 8; ++rr) {
      const int trow = rr * 8 + (lane >> 3);
      bf16x8 v = *(const bf16x8*)((char*)T + trow * 144 + ((lane & 7) << 4));
      *(bf16x8*)(outb + (size_t)(bidx * 1024 + n0 + wc * 64 + trow) * 2048 + srow) = v;
    }
  }
}

// ---------------- flash attention, causal, D=64, QB=128 (4 waves x 32 rows), KB=64 --------
// Q/K come from the fused QK buffer [8192][2048]: Q at cols 0-1023, K at cols 1024-2047.
__global__ __launch_bounds__(256) void attn_kernel(
    const unsigned short* __restrict__ qg, const unsigned short* __restrict__ kg,
    const unsigned short* __restrict__ vT, unsigned short* __restrict__ ctx)
{
  __shared__ char smem[34816];  // K 8KB | V_T 8KB | P 4x4608
  const int bh = blockIdx.x, b = bh >> 4, h = bh & 15;
  const int t = threadIdx.x, lane = t & 63, w = t >> 6, g = lane >> 4, l15 = lane & 15;
  char* Ks = smem;
  char* Vs = smem + 8192;
  char* Ps = smem + 16384 + w * 4608;

  const float SC = 0.18033688011112042f;  // 0.125 * log2(e)

  for (int pass = 0; pass < 2; ++pass) {
    const int qt = pass ? 15 - (int)blockIdx.y : (int)blockIdx.y;
    const int q0 = qt << 7;
    const int q0w = q0 + w * 32;

    bf16x8 qf[2][2];
#pragma unroll
    for (int mi = 0; mi < 2; ++mi)
#pragma unroll
      for (int ks = 0; ks < 2; ++ks)
        qf[mi][ks] = *(const bf16x8*)(qg + (size_t)(b * 2048 + q0w + mi * 16 + l15) * 2048 +
                                      h * 64 + ks * 32 + g * 8);

    f32x4 acc[2][4] = {};
    float lsum[2][4] = {};

    const int ntile = 2 * qt + 2;
    for (int kt = 0; kt < ntile; ++kt) {
      const int kv0 = kt << 6;
      __syncthreads();
#pragma unroll
      for (int it = 0; it < 2; ++it) {
        const int c = it * 256 + t;
        const int row = c >> 3;
        const int wb = (c & 7) << 4;
        const int sw = (wb ^ ((row & 7) << 4)) >> 1;
        gld_lds16(kg + (size_t)(b * 2048 + kv0 + row) * 2048 + h * 64 + sw,
                  Ks + ((it * 256 + w * 64) << 4));
        gld_lds16(vT + (size_t)(b * 1024 + h * 64 + row) * 2048 + kv0 + sw,
                  Vs + ((it * 256 + w * 64) << 4));
      }
      __syncthreads();

      f32x4 sf[2][4] = {};
#pragma unroll
      for (int nb = 0; nb < 4; ++nb) {
        const int krow = nb * 16 + l15;
#pragma unroll
        for (int ks = 0; ks < 2; ++ks) {
          bf16x8 kf = *(const bf16x8*)(Ks + krow * 128 +
                                       (((ks * 32 + g * 8) << 1) ^ ((krow & 7) << 4)));
          sf[0][nb] = MFMA_BF16(qf[0][ks], kf, sf[0][nb]);
          sf[1][nb] = MFMA_BF16(qf[1][ks], kf, sf[1][nb]);
        }
      }
      if (kv0 + 63 > q0w) {
#pragma unroll
        for (int mi = 0; mi < 2; ++mi)
#pragma unroll
          for (int nb = 0; nb < 4; ++nb)
#pragma unroll
            for (int r = 0; r < 4; ++r) {
              const int qq = q0w + mi * 16 + 4 * g + r;
              const int kk = kv0 + nb * 16 + l15;
              if (kk > qq) sf[mi][nb][r] = -__builtin_inff();
            }
      }
#pragma unroll
      for (int mi = 0; mi < 2; ++mi)
#pragma unroll
        for (int nb = 0; nb < 4; ++nb)
#pragma unroll
          for (int r = 0; r < 4; ++r) {
            const float p = exp2f(__builtin_fmaf(sf[mi][nb][r], SC, -4.0f));
            sf[mi][nb][r] = p;
            lsum[mi][r] += p;
          }
#pragma unroll
      for (int mi = 0; mi < 2; ++mi)
#pragma unroll
        for (int nb = 0; nb < 4; ++nb)
#pragma unroll
          for (int r = 0; r < 4; ++r)
            *(unsigned short*)(Ps + (mi * 16 + 4 * g + r) * 144 + ((nb * 16 + l15) << 1)) =
                bf16rn(sf[mi][nb][r]);
      asm volatile("s_waitcnt lgkmcnt(0)" ::: "memory");
#pragma unroll
      for (int mi = 0; mi < 2; ++mi)
#pragma unroll
        for (int ks = 0; ks < 2; ++ks) {
          bf16x8 pa = *(const bf16x8*)(Ps + (mi * 16 + l15) * 144 + ((ks * 32 + g * 8) << 1));
#pragma unroll
          for (int nb = 0; nb < 4; ++nb) {
            const int drow = nb * 16 + l15;
            bf16x8 vb = *(const bf16x8*)(Vs + drow * 128 +
                                         (((ks * 32 + g * 8) << 1) ^ ((drow & 7) << 4)));
            acc[mi][nb] = MFMA_BF16(pa, vb, acc[mi][nb]);
          }
        }
    }
#pragma unroll
    for (int mi = 0; mi < 2; ++mi)
#pragma unroll
      for (int r = 0; r < 4; ++r) {
        float s = lsum[mi][r];
        s += __shfl_xor(s, 1);
        s += __shfl_xor(s, 2);
        s += __shfl_xor(s, 4);
        s += __shfl_xor(s, 8);
        lsum[mi][r] = s;
      }
#pragma unroll
    for (int mi = 0; mi < 2; ++mi) {
      float inv[4];
#pragma unroll
      for (int r = 0; r < 4; ++r) inv[r] = 1.0f / lsum[mi][r];
#pragma unroll
      for (int nb = 0; nb < 4; ++nb)
#pragma unroll
        for (int r = 0; r < 4; ++r)
          ctx[(size_t)(b * 2048 + q0w + mi * 16 + 4 * g + r) * 1024 + h * 64 + nb * 16 + l15] =
              bf16rn(acc[mi][nb][r] * inv[r]);
    }
  }
}

extern "C" void kernel_launch(void* const* d_in, const int* in_sizes, int n_in,
                              void* d_out, int out_size, void* d_ws, size_t ws_size,
                              hipStream_t stream)
{
  const float* x   = (const float*)d_in[0];
  const float* l1s = (const float*)d_in[1];
  const float* l1b = (const float*)d_in[2];
  const float* l2s = (const float*)d_in[3];
  const float* l2b = (const float*)d_in[4];
  const float* Wq  = (const float*)d_in[5];
  const float* Wk  = (const float*)d_in[6];
  const float* Wv  = (const float*)d_in[7];
  const float* Wo  = (const float*)d_in[8];
  const float* bo  = (const float*)d_in[9];
  const float* Wfc = (const float*)d_in[10];
  const float* bfc = (const float*)d_in[11];
  const float* Wpj = (const float*)d_in[12];
  const float* bpj = (const float*)d_in[13];
  float* out = (float*)d_out;
  char* ws = (char*)d_ws;

  // workspace layout (bytes)
  unsigned short* wT   = (unsigned short*)ws;                // 24MB: [wqT wkT][wvT][woT][wfcT][wpjT]
  unsigned short* wqkT = wT;                                 // [2048][1024] fused Q|K
  unsigned short* wvT  = wT + 2097152u;
  unsigned short* woT  = wT + 3145728u;
  unsigned short* wfcT = wT + 4194304u;
  unsigned short* wpjT = wT + 8388608u;
  unsigned short* ln1x = (unsigned short*)(ws + 25165824u);  // 16MB
  unsigned short* qkb  = (unsigned short*)(ws + 41943040u);  // 32MB [8192][2048] fused Q|K out
  unsigned short* vTb  = (unsigned short*)(ws + 75497472u);  // 16MB [b*1024+h*64+d][2048]
  unsigned short* ctx  = (unsigned short*)(ws + 92274688u);  // 16MB (reused as ln2x)
  unsigned short* ln2x = ctx;
  float* hbuf          = (float*)(ws + 109051904u);          // 32MB
  unsigned short* fcb  = (unsigned short*)(ws + 25165824u);  // 64MB, reuses ln1x..vTb region

  convT_kernel<<<3072, 256, 0, stream>>>(Wq, Wk, Wv, Wo, Wfc, Wpj, wT);
  ln_kernel<<<8192, 256, 0, stream>>>(x, l1s, l1b, ln1x);
  // fused Q+K GEMM: [8192][1024] x [2048][1024]^T -> [8192][2048]
  gemm_bt<0><<<1024, 256, 0, stream>>>(ln1x, wqkT, 8192, 2048, 1024,
                                       qkb, nullptr, nullptr, nullptr);
  gemm_bt<1><<<512, 256, 0, stream>>>(ln1x, wvT, 8192, 1024, 1024,
                                      vTb, nullptr, nullptr, nullptr);
  attn_kernel<<<dim3(64, 8), 256, 0, stream>>>(qkb, qkb + 1024, vTb, ctx);
  gemm_bt<2><<<512, 256, 0, stream>>>(ctx, woT, 8192, 1024, 1024,
                                      nullptr, hbuf, bo, x);
  ln_kernel<<<8192, 256, 0, stream>>>(hbuf, l2s, l2b, ln2x);
  gemm_bt<3><<<2048, 256, 0, stream>>>(ln2x, wfcT, 8192, 4096, 1024,
                                       fcb, nullptr, bfc, nullptr);
  gemm_bt<2><<<512, 256, 0, stream>>>(fcb, wpjT, 8192, 1024, 4096,
                                      nullptr, out, bpj, hbuf);
}

// Round 11
// 391.704 us; speedup vs baseline: 1.1648x; 1.1648x over previous
//
#include <hip/hip_runtime.h>

typedef __attribute__((ext_vector_type(8))) short bf16x8;
typedef __attribute__((ext_vector_type(4))) float f32x4;

#define MFMA_BF16(a, b, c) __builtin_amdgcn_mfma_f32_16x16x32_bf16((a), (b), (c), 0, 0, 0)
#define VMCNT(N) asm volatile("s_waitcnt vmcnt(" #N ")" ::: "memory")
#define BAR() asm volatile("s_barrier" ::: "memory")

__device__ __forceinline__ unsigned short bf16rn(float f) {
  unsigned u = __builtin_bit_cast(unsigned, f);
  u += 0x7fffu + ((u >> 16) & 1u);
  return (unsigned short)(u >> 16);
}

__device__ __forceinline__ void gld_lds16(const void* g, void* l) {
  __builtin_amdgcn_global_load_lds((const __attribute__((address_space(1))) void*)g,
                                   (__attribute__((address_space(3))) void*)l, 16, 0, 0);
}

// ---------------- weight convert + transpose: W[K][N] f32 -> W^T[N][K] bf16 ----------------
__global__ __launch_bounds__(256) void convT_kernel(
    const float* __restrict__ wq, const float* __restrict__ wk,
    const float* __restrict__ wv, const float* __restrict__ wo,
    const float* __restrict__ wfc, const float* __restrict__ wpj,
    unsigned short* __restrict__ wsb)
{
  const int bid = blockIdx.x;
  const float* src; unsigned short* dst; int K, N, lb;
  if (bid < 1024) {
    const int m = bid >> 8; lb = bid & 255; K = 1024; N = 1024;
    src = (m == 0) ? wq : (m == 1) ? wk : (m == 2) ? wv : wo;
    dst = wsb + (size_t)m * 1048576u;
  } else if (bid < 2048) {
    lb = bid - 1024; K = 1024; N = 4096; src = wfc; dst = wsb + 4194304u;
  } else {
    lb = bid - 2048; K = 4096; N = 1024; src = wpj; dst = wsb + 8388608u;
  }
  const int tiles_k = K >> 6;
  const int tk = lb % tiles_k, tn = lb / tiles_k;
  const int k0 = tk << 6, n0 = tn << 6;
  const int t = threadIdx.x, kq = t & 15, nq = t >> 4;
  float4 r[4];
#pragma unroll
  for (int i = 0; i < 4; ++i)
    r[i] = *(const float4*)(src + (size_t)(k0 + kq * 4 + i) * N + n0 + nq * 4);
#pragma unroll
  for (int j = 0; j < 4; ++j) {
    ushort4 o;
    o.x = bf16rn(((const float*)&r[0])[j]);
    o.y = bf16rn(((const float*)&r[1])[j]);
    o.z = bf16rn(((const float*)&r[2])[j]);
    o.w = bf16rn(((const float*)&r[3])[j]);
    *(ushort4*)(dst + (size_t)(n0 + nq * 4 + j) * K + k0 + kq * 4) = o;
  }
}

// ---------------- layernorm: f32 [rows][1024] -> bf16 ----------------
__global__ __launch_bounds__(256) void ln_kernel(
    const float* __restrict__ x, const float* __restrict__ sc,
    const float* __restrict__ sh, unsigned short* __restrict__ out)
{
  const int row = blockIdx.x, t = threadIdx.x;
  const float4 v = *(const float4*)(x + (size_t)row * 1024 + t * 4);
  float s = v.x + v.y + v.z + v.w;
  float q = v.x * v.x + v.y * v.y + v.z * v.z + v.w * v.w;
#pragma unroll
  for (int off = 1; off < 64; off <<= 1) { s += __shfl_xor(s, off); q += __shfl_xor(q, off); }
  __shared__ float ps[4], pq[4];
  if ((t & 63) == 0) { ps[t >> 6] = s; pq[t >> 6] = q; }
  __syncthreads();
  s = ps[0] + ps[1] + ps[2] + ps[3];
  q = pq[0] + pq[1] + pq[2] + pq[3];
  const float mean = s * (1.f / 1024.f);
  const float var = q * (1.f / 1024.f) - mean * mean;
  const float inv = rsqrtf(var + 1e-5f);
  const float4 scv = *(const float4*)(sc + t * 4);
  const float4 shv = *(const float4*)(sh + t * 4);
  ushort4 o;
  o.x = bf16rn((v.x - mean) * inv * scv.x + shv.x);
  o.y = bf16rn((v.y - mean) * inv * scv.y + shv.y);
  o.z = bf16rn((v.z - mean) * inv * scv.z + shv.z);
  o.w = bf16rn((v.w - mean) * inv * scv.w + shv.w);
  *(ushort4*)(out + (size_t)row * 1024 + t * 4) = o;
}

// ---------------- 128x128 GEMM, kept only for V (EPI=1: transposed store) -----------------
template<int EPI>
__global__ __launch_bounds__(256) void gemm_bt(
    const unsigned short* __restrict__ A, const unsigned short* __restrict__ Bt,
    int M, int N, int K,
    unsigned short* __restrict__ outb, float* __restrict__ outf,
    const float* __restrict__ bias, const float* __restrict__ resid)
{
  __shared__ char smem[36864];
  const int t = threadIdx.x;
  const int lane = t & 63, w = t >> 6;
  const int g = lane >> 4, l15 = lane & 15;
  const int wr = w >> 1, wc = w & 1;
  const int bid = blockIdx.x;
  const int j = bid >> 3;
  const int tm = (bid & 7) * 8 + (j & 7);
  const int tn = j >> 3;
  const int m0 = tm * 128, n0 = tn * 128;

  f32x4 acc[4][4] = {};

  const int nkt = K >> 5;
  for (int kt = 0; kt < nkt; ++kt) {
    const int k0 = kt << 5;
    __syncthreads();
#pragma unroll
    for (int it = 0; it < 2; ++it) {
      const int c = it * 256 + t;
      const int row = c >> 2;
      const int ce = (c & 3) << 3;
      gld_lds16(A + (size_t)(m0 + row) * K + k0 + ce,
                smem + ((it * 256 + w * 64) << 4));
      gld_lds16(Bt + (size_t)(n0 + row) * K + k0 + ce,
                smem + 8192 + ((it * 256 + w * 64) << 4));
    }
    __syncthreads();
    bf16x8 a[4], b[4];
#pragma unroll
    for (int mi = 0; mi < 4; ++mi)
      a[mi] = *(const bf16x8*)(smem + (wr * 64 + mi * 16 + l15) * 64 + g * 16);
#pragma unroll
    for (int ni = 0; ni < 4; ++ni)
      b[ni] = *(const bf16x8*)(smem + 8192 + (wc * 64 + ni * 16 + l15) * 64 + g * 16);
#pragma unroll
    for (int mi = 0; mi < 4; ++mi)
#pragma unroll
      for (int ni = 0; ni < 4; ++ni)
        acc[mi][ni] = MFMA_BF16(a[mi], b[ni], acc[mi][ni]);
  }

  if constexpr (EPI == 1) {  // transposed store for V
    __syncthreads();
    unsigned short* T = (unsigned short*)(smem + w * 9216);  // [64 n][72 m-padded]
#pragma unroll
    for (int mi = 0; mi < 4; ++mi)
#pragma unroll
      for (int ni = 0; ni < 4; ++ni)
#pragma unroll
        for (int r = 0; r < 4; ++r)
          T[(ni * 16 + l15) * 72 + mi * 16 + 4 * g + r] = bf16rn(acc[mi][ni][r]);
    asm volatile("s_waitcnt lgkmcnt(0)" ::: "memory");
    const int bidx = m0 >> 11;
    const int srow = (m0 & 2047) + wr * 64 + ((lane & 7) << 3);
#pragma unroll
    for (int rr = 0; rr < 8; ++rr) {
      const int trow = rr * 8 + (lane >> 3);
      bf16x8 v = *(const bf16x8*)((char*)T + trow * 144 + ((lane & 7) << 4));
      *(bf16x8*)(outb + (size_t)(bidx * 1024 + n0 + wc * 64 + trow) * 2048 + srow) = v;
    }
  }
}

// ---------------- BMx256 BK=64 quadrant-phase GEMM, deep-prefetch counted-vmcnt ----------
// LDS buf: A [BM rows][128B] + B [256][128B]; 2 buffers. Swizzle: slot' = slot ^ (row&7)
// on stage SOURCE col and frag reads (conflict-free, R9-verified 0 conflicts).
// BM=256, 4 phases/K-tile (quadrants 00,10,11,01):
//   p0: read A(q0)8+B(q0)4              p1: read A(q1)8
//   p2: read B(q1)4 | stage A(kt+2)->cb p3: stage B(kt+2)->cb | VMCNT(8)
// Region-safety: A of cb dead after p1 (reads lgkm'd pre-barrier), B dead after p2.
// Gate ledger: tile kt+1's 8 ops issued kt-1 p2/p3, proven at kt-p3 with 8 newer ops
// in flight (kt+2's) -> VMCNT(8), distance 4-5 phases (~1000+cy > HBM latency).
// BM=128, 2 phases (qn halves): p0: read A 8 + B(q0)4, stage B(kt+1)->ob;
//   p1: read B(q1)4, stage A(kt+2)->cb, VMCNT(2).
// EPI 0: bf16; 2: f32 = acc+bias+resid; 3: bf16 = gelu(acc+bias)
template<int EPI, int BM>
__global__ __launch_bounds__(512, 2) void g8p(
    const unsigned short* __restrict__ A, const unsigned short* __restrict__ Bt,
    int N, int K, int stripeLg,
    unsigned short* __restrict__ outb, float* __restrict__ outf,
    const float* __restrict__ bias, const float* __restrict__ resid)
{
  extern __shared__ char smem[];
  constexpr int ABYTES = BM * 128;
  constexpr int BUFSZ = ABYTES + 32768;
  constexpr int ACH = BM / 64;
  const int t = threadIdx.x, lane = t & 63, w = t >> 6;
  const int g = lane >> 4, l15 = lane & 15;
  const int wr = w >> 2, wc = w & 3;  // 2M x 4N waves; wave tile (BM/2) x 64
  const int bid = blockIdx.x;
  const int tm = ((bid & 7) << stripeLg) + ((bid >> 3) & ((1 << stripeLg) - 1));
  const int tn = bid >> (3 + stripeLg);
  const int m0 = tm * BM, n0 = tn << 8;

  // staging: 8 lanes/row, slot t&7 pulls source k-block (slot ^ row&7) -> full 128B lines
  const int srow = t >> 3;
  const int colswz = (((t & 7) ^ (srow & 7)) << 3);
  const unsigned short* pA = A + (size_t)(m0 + srow) * K + colswz;
  const unsigned short* pB = Bt + (size_t)(n0 + srow) * K + colswz;
  const int ldw = w << 10;

  auto stageA = [&](int TT, char* buf) {
#pragma unroll
    for (int i = 0; i < ACH; ++i)
      gld_lds16(pA + TT * 64 + (size_t)(i * 64) * K, buf + i * 8192 + ldw);
  };
  auto stageB = [&](int TT, char* buf) {
#pragma unroll
    for (int i = 0; i < 4; ++i)
      gld_lds16(pB + TT * 64 + (size_t)(i * 64) * K, buf + ABYTES + i * 8192 + ldw);
  };

  // frag-read slot bytes (lane-constant)
  const int sw0 = (((0 + g) ^ (l15 & 7)) << 4);
  const int sw1 = (((4 + g) ^ (l15 & 7)) << 4);
  const int NT = K >> 6;

#define LDA_Q(CB, QM, AV) { _Pragma("unroll") for (int mi = 0; mi < 4; ++mi) {            \
    const int row_ = (wr * (BM / 2) + (QM) * 64 + mi * 16 + l15) * 128;                   \
    AV[mi][0] = *(const bf16x8*)((CB) + row_ + sw0);                                      \
    AV[mi][1] = *(const bf16x8*)((CB) + row_ + sw1); } }
#define LDB_Q(CB, QN, BV) { _Pragma("unroll") for (int ni = 0; ni < 2; ++ni) {            \
    const int row_ = ABYTES + (wc * 64 + (QN) * 32 + ni * 16 + l15) * 128;                \
    BV[ni][0] = *(const bf16x8*)((CB) + row_ + sw0);                                      \
    BV[ni][1] = *(const bf16x8*)((CB) + row_ + sw1); } }

  if constexpr (BM == 256) {
    f32x4 acc[8][4] = {};
    bf16x8 aq0[4][2], aq1[4][2], bq0[2][2], bq1[2][2];
#define MMQ(AV, BV, QM, QN) { __builtin_amdgcn_s_setprio(1);                              \
    _Pragma("unroll") for (int mi = 0; mi < 4; ++mi)                                      \
      _Pragma("unroll") for (int ni = 0; ni < 2; ++ni) {                                  \
        acc[(QM)*4+mi][(QN)*2+ni] = MFMA_BF16(AV[mi][0], BV[ni][0], acc[(QM)*4+mi][(QN)*2+ni]); \
        acc[(QM)*4+mi][(QN)*2+ni] = MFMA_BF16(AV[mi][1], BV[ni][1], acc[(QM)*4+mi][(QN)*2+ni]); } \
    __builtin_amdgcn_s_setprio(0); }

    stageA(0, smem); stageB(0, smem);
    stageA(1, smem + BUFSZ); stageB(1, smem + BUFSZ);
    VMCNT(8);  // prove tile 0; tile 1 in flight
    BAR();
    for (int kt = 0; kt < NT; ++kt) {
      char* cb = smem + (kt & 1) * BUFSZ;
      // p0
      LDA_Q(cb, 0, aq0);
      LDB_Q(cb, 0, bq0);
      BAR();
      MMQ(aq0, bq0, 0, 0);
      BAR();
      // p1
      LDA_Q(cb, 1, aq1);
      BAR();
      MMQ(aq1, bq0, 1, 0);
      BAR();
      // p2 (A region of cb dead -> stage tile kt+2's A)
      LDB_Q(cb, 1, bq1);
      if (kt + 2 < NT) stageA(kt + 2, cb);
      BAR();
      MMQ(aq1, bq1, 1, 1);
      BAR();
      // p3 (B region dead -> stage B; single per-tile gate proves tile kt+1)
      if (kt + 2 < NT) { stageB(kt + 2, cb); VMCNT(8); }
      else if (kt + 1 < NT) VMCNT(0);
      BAR();
      MMQ(aq0, bq1, 0, 1);
      BAR();
    }
#undef MMQ
    // epilogue
    if constexpr (EPI == 2) {
#pragma unroll
      for (int ai = 0; ai < 8; ++ai) {
        const int ro = ((ai >> 2) << 6) + ((ai & 3) << 4) + g * 4;
#pragma unroll
        for (int ci = 0; ci < 4; ++ci) {
          const int n = n0 + wc * 64 + ((ci >> 1) << 5) + ((ci & 1) << 4) + l15;
          const float bn = bias[n];
#pragma unroll
          for (int r = 0; r < 4; ++r) {
            const size_t m = m0 + wr * 128 + ro + r;
            outf[m * N + n] = acc[ai][ci][r] + bn + resid[m * N + n];
          }
        }
      }
    } else {
      __syncthreads();
      char* wsl = smem + w * 16384;  // [128][64] bf16 bounce
#pragma unroll
      for (int ai = 0; ai < 8; ++ai) {
        const int ro = ((ai >> 2) << 6) + ((ai & 3) << 4) + g * 4;
#pragma unroll
        for (int ci = 0; ci < 4; ++ci) {
          const int co = ((ci >> 1) << 5) + ((ci & 1) << 4) + l15;
          float bn = 0.f;
          if constexpr (EPI == 3) bn = bias[n0 + wc * 64 + co];
#pragma unroll
          for (int r = 0; r < 4; ++r) {
            float v = acc[ai][ci][r];
            if constexpr (EPI == 3) {
              v += bn;
              const float inner = 0.7978845608028654f * (v + 0.044715f * v * v * v);
              v = 0.5f * v * (1.0f + tanhf(inner));
            }
            *(unsigned short*)(wsl + (ro + r) * 128 + co * 2) = bf16rn(v);
          }
        }
      }
#pragma unroll
      for (int s = 0; s < 16; ++s) {
        const int row = s * 8 + (lane >> 3);
        bf16x8 vv = *(const bf16x8*)(wsl + row * 128 + (lane & 7) * 16);
        *(bf16x8*)(outb + (size_t)(m0 + wr * 128 + row) * N + n0 + wc * 64 + (lane & 7) * 8) = vv;
      }
    }
  } else {  // BM == 128: 2 phases
    f32x4 acc[4][4] = {};
    bf16x8 aq[4][2], bq0[2][2], bq1[2][2];
#define MMQ128(BV, QN) { __builtin_amdgcn_s_setprio(1);                                   \
    _Pragma("unroll") for (int mi = 0; mi < 4; ++mi)                                      \
      _Pragma("unroll") for (int ni = 0; ni < 2; ++ni) {                                  \
        acc[mi][(QN)*2+ni] = MFMA_BF16(aq[mi][0], BV[ni][0], acc[mi][(QN)*2+ni]);         \
        acc[mi][(QN)*2+ni] = MFMA_BF16(aq[mi][1], BV[ni][1], acc[mi][(QN)*2+ni]); }       \
    __builtin_amdgcn_s_setprio(0); }

    stageA(0, smem); stageB(0, smem);
    stageA(1, smem + BUFSZ);
    VMCNT(2);  // prove tile 0; tile 1's A in flight
    BAR();
    for (int kt = 0; kt < NT; ++kt) {
      char* cb = smem + (kt & 1) * BUFSZ;
      char* ob = smem + ((kt & 1) ^ 1) * BUFSZ;
      // p0: B of ob dead since kt-1 -> stage B(kt+1)
      LDA_Q(cb, 0, aq);
      LDB_Q(cb, 0, bq0);
      if (kt + 1 < NT) stageB(kt + 1, ob);
      BAR();
      MMQ128(bq0, 0);
      BAR();
      // p1: A of cb dead -> stage A(kt+2); gate proves tile kt+1 (2 newer ops)
      LDB_Q(cb, 1, bq1);
      if (kt + 2 < NT) { stageA(kt + 2, cb); VMCNT(2); }
      else if (kt + 1 < NT) VMCNT(0);
      BAR();
      MMQ128(bq1, 1);
      BAR();
    }
#undef MMQ128
    if constexpr (EPI == 2) {
#pragma unroll
      for (int mi = 0; mi < 4; ++mi) {
        const int ro = mi * 16 + g * 4;
#pragma unroll
        for (int ci = 0; ci < 4; ++ci) {
          const int n = n0 + wc * 64 + ((ci >> 1) << 5) + ((ci & 1) << 4) + l15;
          const float bn = bias[n];
#pragma unroll
          for (int r = 0; r < 4; ++r) {
            const size_t m = m0 + wr * 64 + ro + r;
            outf[m * N + n] = acc[mi][ci][r] + bn + resid[m * N + n];
          }
        }
      }
    } else {
      __syncthreads();
      char* wsl = smem + w * 8192;  // [64][64] bf16 bounce
#pragma unroll
      for (int mi = 0; mi < 4; ++mi) {
        const int ro = mi * 16 + g * 4;
#pragma unroll
        for (int ci = 0; ci < 4; ++ci) {
          const int co = ((ci >> 1) << 5) + ((ci & 1) << 4) + l15;
          float bn = 0.f;
          if constexpr (EPI == 3) bn = bias[n0 + wc * 64 + co];
#pragma unroll
          for (int r = 0; r < 4; ++r) {
            float v = acc[mi][ci][r];
            if constexpr (EPI == 3) {
              v += bn;
              const float inner = 0.7978845608028654f * (v + 0.044715f * v * v * v);
              v = 0.5f * v * (1.0f + tanhf(inner));
            }
            *(unsigned short*)(wsl + (ro + r) * 128 + co * 2) = bf16rn(v);
          }
        }
      }
#pragma unroll
      for (int s = 0; s < 8; ++s) {
        const int row = s * 8 + (lane >> 3);
        bf16x8 vv = *(const bf16x8*)(wsl + row * 128 + (lane & 7) * 16);
        *(bf16x8*)(outb + (size_t)(m0 + wr * 64 + row) * N + n0 + wc * 64 + (lane & 7) * 8) = vv;
      }
    }
  }
#undef LDA_Q
#undef LDB_Q
}

// ---------------- flash attention, causal, D=64, QB=128 (4 waves x 32 rows), KB=64 --------
__global__ __launch_bounds__(256) void attn_kernel(
    const unsigned short* __restrict__ qg, const unsigned short* __restrict__ kg,
    const unsigned short* __restrict__ vT, unsigned short* __restrict__ ctx)
{
  __shared__ char smem[34816];  // K 8KB | V_T 8KB | P 4x4608
  const int bh = blockIdx.x, b = bh >> 4, h = bh & 15;
  const int t = threadIdx.x, lane = t & 63, w = t >> 6, g = lane >> 4, l15 = lane & 15;
  char* Ks = smem;
  char* Vs = smem + 8192;
  char* Ps = smem + 16384 + w * 4608;

  const float SC = 0.18033688011112042f;  // 0.125 * log2(e)

  for (int pass = 0; pass < 2; ++pass) {
    const int qt = pass ? 15 - (int)blockIdx.y : (int)blockIdx.y;
    const int q0 = qt << 7;
    const int q0w = q0 + w * 32;

    bf16x8 qf[2][2];
#pragma unroll
    for (int mi = 0; mi < 2; ++mi)
#pragma unroll
      for (int ks = 0; ks < 2; ++ks)
        qf[mi][ks] = *(const bf16x8*)(qg + (size_t)(b * 2048 + q0w + mi * 16 + l15) * 2048 +
                                      h * 64 + ks * 32 + g * 8);

    f32x4 acc[2][4] = {};
    float lsum[2][4] = {};

    const int ntile = 2 * qt + 2;
    for (int kt = 0; kt < ntile; ++kt) {
      const int kv0 = kt << 6;
      __syncthreads();
#pragma unroll
      for (int it = 0; it < 2; ++it) {
        const int c = it * 256 + t;
        const int row = c >> 3;
        const int wb = (c & 7) << 4;
        const int sw = (wb ^ ((row & 7) << 4)) >> 1;
        gld_lds16(kg + (size_t)(b * 2048 + kv0 + row) * 2048 + h * 64 + sw,
                  Ks + ((it * 256 + w * 64) << 4));
        gld_lds16(vT + (size_t)(b * 1024 + h * 64 + row) * 2048 + kv0 + sw,
                  Vs + ((it * 256 + w * 64) << 4));
      }
      __syncthreads();

      f32x4 sf[2][4] = {};
#pragma unroll
      for (int nb = 0; nb < 4; ++nb) {
        const int krow = nb * 16 + l15;
#pragma unroll
        for (int ks = 0; ks < 2; ++ks) {
          bf16x8 kf = *(const bf16x8*)(Ks + krow * 128 +
                                       (((ks * 32 + g * 8) << 1) ^ ((krow & 7) << 4)));
          sf[0][nb] = MFMA_BF16(qf[0][ks], kf, sf[0][nb]);
          sf[1][nb] = MFMA_BF16(qf[1][ks], kf, sf[1][nb]);
        }
      }
      if (kv0 + 63 > q0w) {
#pragma unroll
        for (int mi = 0; mi < 2; ++mi)
#pragma unroll
          for (int nb = 0; nb < 4; ++nb)
#pragma unroll
            for (int r = 0; r < 4; ++r) {
              const int qq = q0w + mi * 16 + 4 * g + r;
              const int kk = kv0 + nb * 16 + l15;
              if (kk > qq) sf[mi][nb][r] = -__builtin_inff();
            }
      }
#pragma unroll
      for (int mi = 0; mi < 2; ++mi)
#pragma unroll
        for (int nb = 0; nb < 4; ++nb)
#pragma unroll
          for (int r = 0; r < 4; ++r) {
            const float p = exp2f(__builtin_fmaf(sf[mi][nb][r], SC, -4.0f));
            sf[mi][nb][r] = p;
            lsum[mi][r] += p;
          }
#pragma unroll
      for (int mi = 0; mi < 2; ++mi)
#pragma unroll
        for (int nb = 0; nb < 4; ++nb)
#pragma unroll
          for (int r = 0; r < 4; ++r)
            *(unsigned short*)(Ps + (mi * 16 + 4 * g + r) * 144 + ((nb * 16 + l15) << 1)) =
                bf16rn(sf[mi][nb][r]);
      asm volatile("s_waitcnt lgkmcnt(0)" ::: "memory");
#pragma unroll
      for (int mi = 0; mi < 2; ++mi)
#pragma unroll
        for (int ks = 0; ks < 2; ++ks) {
          bf16x8 pa = *(const bf16x8*)(Ps + (mi * 16 + l15) * 144 + ((ks * 32 + g * 8) << 1));
#pragma unroll
          for (int nb = 0; nb < 4; ++nb) {
            const int drow = nb * 16 + l15;
            bf16x8 vb = *(const bf16x8*)(Vs + drow * 128 +
                                         (((ks * 32 + g * 8) << 1) ^ ((drow & 7) << 4)));
            acc[mi][nb] = MFMA_BF16(pa, vb, acc[mi][nb]);
          }
        }
    }
#pragma unroll
    for (int mi = 0; mi < 2; ++mi)
#pragma unroll
      for (int r = 0; r < 4; ++r) {
        float s = lsum[mi][r];
        s += __shfl_xor(s, 1);
        s += __shfl_xor(s, 2);
        s += __shfl_xor(s, 4);
        s += __shfl_xor(s, 8);
        lsum[mi][r] = s;
      }
#pragma unroll
    for (int mi = 0; mi < 2; ++mi) {
      float inv[4];
#pragma unroll
      for (int r = 0; r < 4; ++r) inv[r] = 1.0f / lsum[mi][r];
#pragma unroll
      for (int nb = 0; nb < 4; ++nb)
#pragma unroll
        for (int r = 0; r < 4; ++r)
          ctx[(size_t)(b * 2048 + q0w + mi * 16 + 4 * g + r) * 1024 + h * 64 + nb * 16 + l15] =
              bf16rn(acc[mi][nb][r] * inv[r]);
    }
  }
}

extern "C" void kernel_launch(void* const* d_in, const int* in_sizes, int n_in,
                              void* d_out, int out_size, void* d_ws, size_t ws_size,
                              hipStream_t stream)
{
  const float* x   = (const float*)d_in[0];
  const float* l1s = (const float*)d_in[1];
  const float* l1b = (const float*)d_in[2];
  const float* l2s = (const float*)d_in[3];
  const float* l2b = (const float*)d_in[4];
  const float* Wq  = (const float*)d_in[5];
  const float* Wk  = (const float*)d_in[6];
  const float* Wv  = (const float*)d_in[7];
  const float* Wo  = (const float*)d_in[8];
  const float* bo  = (const float*)d_in[9];
  const float* Wfc = (const float*)d_in[10];
  const float* bfc = (const float*)d_in[11];
  const float* Wpj = (const float*)d_in[12];
  const float* bpj = (const float*)d_in[13];
  float* out = (float*)d_out;
  char* ws = (char*)d_ws;

  unsigned short* wT   = (unsigned short*)ws;                // 24MB weights
  unsigned short* wqkT = wT;                                 // [2048][1024] fused Q|K
  unsigned short* wvT  = wT + 2097152u;
  unsigned short* woT  = wT + 3145728u;
  unsigned short* wfcT = wT + 4194304u;
  unsigned short* wpjT = wT + 8388608u;
  unsigned short* ln1x = (unsigned short*)(ws + 25165824u);  // 16MB
  unsigned short* qkb  = (unsigned short*)(ws + 41943040u);  // 32MB [8192][2048]
  unsigned short* vTb  = (unsigned short*)(ws + 75497472u);  // 16MB
  unsigned short* ctx  = (unsigned short*)(ws + 92274688u);  // 16MB (reused as ln2x)
  unsigned short* ln2x = ctx;
  float* hbuf          = (float*)(ws + 109051904u);          // 32MB
  unsigned short* fcb  = (unsigned short*)(ws + 25165824u);  // 64MB, reuses ln1x..vTb

  convT_kernel<<<3072, 256, 0, stream>>>(Wq, Wk, Wv, Wo, Wfc, Wpj, wT);
  ln_kernel<<<8192, 256, 0, stream>>>(x, l1s, l1b, ln1x);
  g8p<0, 256><<<256, 512, 131072, stream>>>(ln1x, wqkT, 2048, 1024, 2,
                                            qkb, nullptr, nullptr, nullptr);
  gemm_bt<1><<<512, 256, 0, stream>>>(ln1x, wvT, 8192, 1024, 1024,
                                      vTb, nullptr, nullptr, nullptr);
  attn_kernel<<<dim3(64, 8), 256, 0, stream>>>(qkb, qkb + 1024, vTb, ctx);
  g8p<2, 128><<<256, 512, 98304, stream>>>(ctx, woT, 1024, 1024, 3,
                                           nullptr, hbuf, bo, x);
  ln_kernel<<<8192, 256, 0, stream>>>(hbuf, l2s, l2b, ln2x);
  g8p<3, 256><<<512, 512, 131072, stream>>>(ln2x, wfcT, 4096, 1024, 2,
                                            fcb, nullptr, bfc, nullptr);
  g8p<2, 128><<<256, 512, 98304, stream>>>(fcb, wpjT, 1024, 4096, 3,
                                           nullptr, out, bpj, hbuf);
}

// Round 12
// 380.185 us; speedup vs baseline: 1.2001x; 1.0303x over previous
//
#include <hip/hip_runtime.h>

typedef __attribute__((ext_vector_type(8))) short bf16x8;
typedef __attribute__((ext_vector_type(4))) float f32x4;

#define MFMA_BF16(a, b, c) __builtin_amdgcn_mfma_f32_16x16x32_bf16((a), (b), (c), 0, 0, 0)
#define VMCNT(N) asm volatile("s_waitcnt vmcnt(" #N ")" ::: "memory")
#define BAR() asm volatile("s_barrier" ::: "memory")

__device__ __forceinline__ unsigned short bf16rn(float f) {
  unsigned u = __builtin_bit_cast(unsigned, f);
  u += 0x7fffu + ((u >> 16) & 1u);
  return (unsigned short)(u >> 16);
}

__device__ __forceinline__ void gld_lds16(const void* g, void* l) {
  __builtin_amdgcn_global_load_lds((const __attribute__((address_space(1))) void*)g,
                                   (__attribute__((address_space(3))) void*)l, 16, 0, 0);
}

// ---------------- weight convert + transpose: W[K][N] f32 -> W^T[N][K] bf16 ----------------
__global__ __launch_bounds__(256) void convT_kernel(
    const float* __restrict__ wq, const float* __restrict__ wk,
    const float* __restrict__ wv, const float* __restrict__ wo,
    const float* __restrict__ wfc, const float* __restrict__ wpj,
    unsigned short* __restrict__ wsb)
{
  const int bid = blockIdx.x;
  const float* src; unsigned short* dst; int K, N, lb;
  if (bid < 1024) {
    const int m = bid >> 8; lb = bid & 255; K = 1024; N = 1024;
    src = (m == 0) ? wq : (m == 1) ? wk : (m == 2) ? wv : wo;
    dst = wsb + (size_t)m * 1048576u;
  } else if (bid < 2048) {
    lb = bid - 1024; K = 1024; N = 4096; src = wfc; dst = wsb + 4194304u;
  } else {
    lb = bid - 2048; K = 4096; N = 1024; src = wpj; dst = wsb + 8388608u;
  }
  const int tiles_k = K >> 6;
  const int tk = lb % tiles_k, tn = lb / tiles_k;
  const int k0 = tk << 6, n0 = tn << 6;
  const int t = threadIdx.x, kq = t & 15, nq = t >> 4;
  float4 r[4];
#pragma unroll
  for (int i = 0; i < 4; ++i)
    r[i] = *(const float4*)(src + (size_t)(k0 + kq * 4 + i) * N + n0 + nq * 4);
#pragma unroll
  for (int j = 0; j < 4; ++j) {
    ushort4 o;
    o.x = bf16rn(((const float*)&r[0])[j]);
    o.y = bf16rn(((const float*)&r[1])[j]);
    o.z = bf16rn(((const float*)&r[2])[j]);
    o.w = bf16rn(((const float*)&r[3])[j]);
    *(ushort4*)(dst + (size_t)(n0 + nq * 4 + j) * K + k0 + kq * 4) = o;
  }
}

// ---------------- layernorm: f32 [rows][1024] -> bf16 ----------------
__global__ __launch_bounds__(256) void ln_kernel(
    const float* __restrict__ x, const float* __restrict__ sc,
    const float* __restrict__ sh, unsigned short* __restrict__ out)
{
  const int row = blockIdx.x, t = threadIdx.x;
  const float4 v = *(const float4*)(x + (size_t)row * 1024 + t * 4);
  float s = v.x + v.y + v.z + v.w;
  float q = v.x * v.x + v.y * v.y + v.z * v.z + v.w * v.w;
#pragma unroll
  for (int off = 1; off < 64; off <<= 1) { s += __shfl_xor(s, off); q += __shfl_xor(q, off); }
  __shared__ float ps[4], pq[4];
  if ((t & 63) == 0) { ps[t >> 6] = s; pq[t >> 6] = q; }
  __syncthreads();
  s = ps[0] + ps[1] + ps[2] + ps[3];
  q = pq[0] + pq[1] + pq[2] + pq[3];
  const float mean = s * (1.f / 1024.f);
  const float var = q * (1.f / 1024.f) - mean * mean;
  const float inv = rsqrtf(var + 1e-5f);
  const float4 scv = *(const float4*)(sc + t * 4);
  const float4 shv = *(const float4*)(sh + t * 4);
  ushort4 o;
  o.x = bf16rn((v.x - mean) * inv * scv.x + shv.x);
  o.y = bf16rn((v.y - mean) * inv * scv.y + shv.y);
  o.z = bf16rn((v.z - mean) * inv * scv.z + shv.z);
  o.w = bf16rn((v.w - mean) * inv * scv.w + shv.w);
  *(ushort4*)(out + (size_t)row * 1024 + t * 4) = o;
}

// ---------------- 128x128 GEMM, kept only for V (EPI=1: transposed store) -----------------
template<int EPI>
__global__ __launch_bounds__(256) void gemm_bt(
    const unsigned short* __restrict__ A, const unsigned short* __restrict__ Bt,
    int M, int N, int K,
    unsigned short* __restrict__ outb, float* __restrict__ outf,
    const float* __restrict__ bias, const float* __restrict__ resid)
{
  __shared__ char smem[36864];
  const int t = threadIdx.x;
  const int lane = t & 63, w = t >> 6;
  const int g = lane >> 4, l15 = lane & 15;
  const int wr = w >> 1, wc = w & 1;
  const int bid = blockIdx.x;
  const int j = bid >> 3;
  const int tm = (bid & 7) * 8 + (j & 7);
  const int tn = j >> 3;
  const int m0 = tm * 128, n0 = tn * 128;

  f32x4 acc[4][4] = {};

  const int nkt = K >> 5;
  for (int kt = 0; kt < nkt; ++kt) {
    const int k0 = kt << 5;
    __syncthreads();
#pragma unroll
    for (int it = 0; it < 2; ++it) {
      const int c = it * 256 + t;
      const int row = c >> 2;
      const int ce = (c & 3) << 3;
      gld_lds16(A + (size_t)(m0 + row) * K + k0 + ce,
                smem + ((it * 256 + w * 64) << 4));
      gld_lds16(Bt + (size_t)(n0 + row) * K + k0 + ce,
                smem + 8192 + ((it * 256 + w * 64) << 4));
    }
    __syncthreads();
    bf16x8 a[4], b[4];
#pragma unroll
    for (int mi = 0; mi < 4; ++mi)
      a[mi] = *(const bf16x8*)(smem + (wr * 64 + mi * 16 + l15) * 64 + g * 16);
#pragma unroll
    for (int ni = 0; ni < 4; ++ni)
      b[ni] = *(const bf16x8*)(smem + 8192 + (wc * 64 + ni * 16 + l15) * 64 + g * 16);
#pragma unroll
    for (int mi = 0; mi < 4; ++mi)
#pragma unroll
      for (int ni = 0; ni < 4; ++ni)
        acc[mi][ni] = MFMA_BF16(a[mi], b[ni], acc[mi][ni]);
  }

  if constexpr (EPI == 1) {  // transposed store for V
    __syncthreads();
    unsigned short* T = (unsigned short*)(smem + w * 9216);  // [64 n][72 m-padded]
#pragma unroll
    for (int mi = 0; mi < 4; ++mi)
#pragma unroll
      for (int ni = 0; ni < 4; ++ni)
#pragma unroll
        for (int r = 0; r < 4; ++r)
          T[(ni * 16 + l15) * 72 + mi * 16 + 4 * g + r] = bf16rn(acc[mi][ni][r]);
    asm volatile("s_waitcnt lgkmcnt(0)" ::: "memory");
    const int bidx = m0 >> 11;
    const int srow = (m0 & 2047) + wr * 64 + ((lane & 7) << 3);
#pragma unroll
    for (int rr = 0; rr < 8; ++rr) {
      const int trow = rr * 8 + (lane >> 3);
      bf16x8 v = *(const bf16x8*)((char*)T + trow * 144 + ((lane & 7) << 4));
      *(bf16x8*)(outb + (size_t)(bidx * 1024 + n0 + wc * 64 + trow) * 2048 + srow) = v;
    }
  }
}

// ---------------- 128x128 BK=64 GEMM: 2 blocks/CU + quadrant phases + counted vmcnt ------
// 256 thr / 4 waves (2M x 2N; wave tile 64x64). LDS: 2 buf x (A[128][128B] + B[128][128B])
// = 64KB -> 2 INDEPENDENT blocks per CU (decoupled barrier groups: one block's waves fill
// the SIMD while the other stalls at barriers/lgkm - the m114 overlap mechanism).
// 128B rows + slot'=slot^(row&7) involution on stage SOURCE and reads (0 conflicts,
// verified R9/R11). Per K-tile, 2 phases:
//   p0: read A(all, 8 b128) + B-chunks{0,2} (4) | stage B-chunks{1,3}(t+1)->ob | BAR |
//       16 MFMA (ni 0,1) | BAR
//   p1: read B-chunks{1,3} (4) | stage A(t+2)+B-chunks{0,2}(t+2)->cb | VMCNT(6) | BAR |
//       16 MFMA (ni 2,3) | BAR
// Region-safety (stage-issue always after the barrier that ends the last phase reading
// that region): B13(ob) last read t-1 p1; A(cb),B02(cb) last read t p0. Gate ledger:
// steady-state issue order ...[t-1 p1: A,B02(t+1) x6][t p0: B13(t+1) x2][t p1: A,B02(t+2)
// x6] -> VMCNT(6) leaves only the newest 6 -> tile t+1 fully proven before its p0 reads.
// Tail: t=NT-2 p1: VMCNT(0) on 1-phase-old B13(NT-1) (once). Never 0 elsewhere mid-loop.
// EPI 0: bf16; 2: f32 = acc+bias+resid; 3: bf16 = gelu(acc+bias)
template<int EPI>
__global__ __launch_bounds__(256, 2) void g128(
    const unsigned short* __restrict__ A, const unsigned short* __restrict__ Bt,
    int N, int K,
    unsigned short* __restrict__ outb, float* __restrict__ outf,
    const float* __restrict__ bias, const float* __restrict__ resid)
{
  extern __shared__ char smem[];
  constexpr int BUFSZ = 32768;  // A 16KB + B 16KB
  const int t = threadIdx.x, lane = t & 63, w = t >> 6;
  const int g = lane >> 4, l15 = lane & 15;
  const int wr = w >> 1, wc = w & 1;  // 2M x 2N waves; wave tile 64 x 64
  const int bid = blockIdx.x;
  const int tm = (bid & 7) * 8 + ((bid >> 3) & 7);
  const int tn = bid >> 6;
  const int m0 = tm << 7, n0 = tn << 7;

  // staging: 8 lanes/row (srow = t>>3, slot = t&7); source col (slot ^ row&7)*8 elements
  // -> full 128B lines, LDS content [row][slot] = src[row][slot^(row&7)].
  const int srow = t >> 3;
  const int colswz = (((t & 7) ^ (srow & 7)) << 3);
  const unsigned short* pA = A + (size_t)(m0 + srow) * K + colswz;
  const unsigned short* pB = Bt + (size_t)(n0 + srow) * K + colswz;
  const int ldw = w << 10;  // per-wave 1KB (rows w*8..w*8+7) within a 4KB chunk

  // chunk i covers rows i*32..i*32+31; A chunks 0-3, B chunks 0-3 at +16KB
  auto stA = [&](int TT, char* buf) {
#pragma unroll
    for (int i = 0; i < 4; ++i)
      gld_lds16(pA + TT * 64 + (size_t)(i * 32) * K, buf + i * 4096 + ldw);
  };
  auto stB02 = [&](int TT, char* buf) {
    gld_lds16(pB + TT * 64, buf + 16384 + ldw);
    gld_lds16(pB + TT * 64 + (size_t)64 * K, buf + 16384 + 8192 + ldw);
  };
  auto stB13 = [&](int TT, char* buf) {
    gld_lds16(pB + TT * 64 + (size_t)32 * K, buf + 16384 + 4096 + ldw);
    gld_lds16(pB + TT * 64 + (size_t)96 * K, buf + 16384 + 12288 + ldw);
  };

  // frag-read swizzled slot bytes (lane-constant; row&7 == l15&7 since bases are mult of 16)
  const int sw0 = (((0 + g) ^ (l15 & 7)) << 4);
  const int sw1 = (((4 + g) ^ (l15 & 7)) << 4);
  const int NT = K >> 6;

  f32x4 acc[4][4] = {};
  bf16x8 av[4][2], bv0[2][2], bv1[2][2];

#define LDA_ALL(CB) { _Pragma("unroll") for (int mi = 0; mi < 4; ++mi) {                  \
    const int row_ = (wr * 64 + mi * 16 + l15) * 128;                                     \
    av[mi][0] = *(const bf16x8*)((CB) + row_ + sw0);                                      \
    av[mi][1] = *(const bf16x8*)((CB) + row_ + sw1); } }
#define LDB_H(CB, H, BV) { _Pragma("unroll") for (int ni = 0; ni < 2; ++ni) {             \
    const int row_ = 16384 + (wc * 64 + (H) * 32 + ni * 16 + l15) * 128;                  \
    BV[ni][0] = *(const bf16x8*)((CB) + row_ + sw0);                                      \
    BV[ni][1] = *(const bf16x8*)((CB) + row_ + sw1); } }
#define MMH(BV, H) { __builtin_amdgcn_s_setprio(1);                                       \
    _Pragma("unroll") for (int mi = 0; mi < 4; ++mi)                                      \
      _Pragma("unroll") for (int ni = 0; ni < 2; ++ni) {                                  \
        acc[mi][(H)*2+ni] = MFMA_BF16(av[mi][0], BV[ni][0], acc[mi][(H)*2+ni]);           \
        acc[mi][(H)*2+ni] = MFMA_BF16(av[mi][1], BV[ni][1], acc[mi][(H)*2+ni]);  }        \
    __builtin_amdgcn_s_setprio(0); }

  // prologue: full tile 0 (8 ops) + tile 1's A,B02 (6 ops); prove tile 0
  stA(0, smem); stB02(0, smem); stB13(0, smem);
  stA(1, smem + BUFSZ); stB02(1, smem + BUFSZ);
  VMCNT(6);
  BAR();

  for (int kt = 0; kt < NT; ++kt) {
    char* cb = smem + (kt & 1) * BUFSZ;
    char* ob = smem + ((kt & 1) ^ 1) * BUFSZ;
    // ---- p0: A(all) + B halves 0 (chunks 0,2) ----
    LDA_ALL(cb);
    LDB_H(cb, 0, bv0);
    if (kt + 1 < NT) stB13(kt + 1, ob);  // B13(ob) dead since (kt-1) p1-end barrier
    BAR();
    MMH(bv0, 0);
    BAR();
    // ---- p1: B halves 1 (chunks 1,3) ----
    LDB_H(cb, 1, bv1);
    if (kt + 2 < NT) { stA(kt + 2, cb); stB02(kt + 2, cb); VMCNT(6); }
    else if (kt + 1 < NT) VMCNT(0);  // once, on 1-phase-old B13(NT-1)
    BAR();
    MMH(bv1, 1);
    BAR();
  }
#undef LDA_ALL
#undef LDB_H
#undef MMH

  // epilogue; acc[mi][ci]: row = wr*64 + mi*16 + g*4 + r; col = wc*64 + ci*16 + l15
  if constexpr (EPI == 2) {
#pragma unroll
    for (int mi = 0; mi < 4; ++mi) {
      const int ro = mi * 16 + g * 4;
#pragma unroll
      for (int ci = 0; ci < 4; ++ci) {
        const int n = n0 + wc * 64 + ci * 16 + l15;
        const float bn = bias[n];
#pragma unroll
        for (int r = 0; r < 4; ++r) {
          const size_t m = m0 + wr * 64 + ro + r;
          outf[m * N + n] = acc[mi][ci][r] + bn + resid[m * N + n];
        }
      }
    }
  } else {
    __syncthreads();
    char* wsl = smem + w * 8192;  // per-wave bounce [64 rows][64 cols] bf16
#pragma unroll
    for (int mi = 0; mi < 4; ++mi) {
      const int ro = mi * 16 + g * 4;
#pragma unroll
      for (int ci = 0; ci < 4; ++ci) {
        const int co = ci * 16 + l15;
        float bn = 0.f;
        if constexpr (EPI == 3) bn = bias[n0 + wc * 64 + co];
#pragma unroll
        for (int r = 0; r < 4; ++r) {
          float v = acc[mi][ci][r];
          if constexpr (EPI == 3) {
            v += bn;
            const float inner = 0.7978845608028654f * (v + 0.044715f * v * v * v);
            v = 0.5f * v * (1.0f + tanhf(inner));
          }
          *(unsigned short*)(wsl + (ro + r) * 128 + co * 2) = bf16rn(v);
        }
      }
    }
    // same-wave LDS RAW ordered by compiler lgkmcnt
#pragma unroll
    for (int s = 0; s < 8; ++s) {
      const int row = s * 8 + (lane >> 3);
      bf16x8 vv = *(const bf16x8*)(wsl + row * 128 + (lane & 7) * 16);
      *(bf16x8*)(outb + (size_t)(m0 + wr * 64 + row) * N + n0 + wc * 64 + (lane & 7) * 8) = vv;
    }
  }
}

// ---------------- flash attention, causal, D=64, QB=128 (4 waves x 32 rows), KB=64 --------
__global__ __launch_bounds__(256) void attn_kernel(
    const unsigned short* __restrict__ qg, const unsigned short* __restrict__ kg,
    const unsigned short* __restrict__ vT, unsigned short* __restrict__ ctx)
{
  __shared__ char smem[34816];  // K 8KB | V_T 8KB | P 4x4608
  const int bh = blockIdx.x, b = bh >> 4, h = bh & 15;
  const int t = threadIdx.x, lane = t & 63, w = t >> 6, g = lane >> 4, l15 = lane & 15;
  char* Ks = smem;
  char* Vs = smem + 8192;
  char* Ps = smem + 16384 + w * 4608;

  const float SC = 0.18033688011112042f;  // 0.125 * log2(e)

  for (int pass = 0; pass < 2; ++pass) {
    const int qt = pass ? 15 - (int)blockIdx.y : (int)blockIdx.y;
    const int q0 = qt << 7;
    const int q0w = q0 + w * 32;

    bf16x8 qf[2][2];
#pragma unroll
    for (int mi = 0; mi < 2; ++mi)
#pragma unroll
      for (int ks = 0; ks < 2; ++ks)
        qf[mi][ks] = *(const bf16x8*)(qg + (size_t)(b * 2048 + q0w + mi * 16 + l15) * 2048 +
                                      h * 64 + ks * 32 + g * 8);

    f32x4 acc[2][4] = {};
    float lsum[2][4] = {};

    const int ntile = 2 * qt + 2;
    for (int kt = 0; kt < ntile; ++kt) {
      const int kv0 = kt << 6;
      __syncthreads();
#pragma unroll
      for (int it = 0; it < 2; ++it) {
        const int c = it * 256 + t;
        const int row = c >> 3;
        const int wb = (c & 7) << 4;
        const int sw = (wb ^ ((row & 7) << 4)) >> 1;
        gld_lds16(kg + (size_t)(b * 2048 + kv0 + row) * 2048 + h * 64 + sw,
                  Ks + ((it * 256 + w * 64) << 4));
        gld_lds16(vT + (size_t)(b * 1024 + h * 64 + row) * 2048 + kv0 + sw,
                  Vs + ((it * 256 + w * 64) << 4));
      }
      __syncthreads();

      f32x4 sf[2][4] = {};
#pragma unroll
      for (int nb = 0; nb < 4; ++nb) {
        const int krow = nb * 16 + l15;
#pragma unroll
        for (int ks = 0; ks < 2; ++ks) {
          bf16x8 kf = *(const bf16x8*)(Ks + krow * 128 +
                                       (((ks * 32 + g * 8) << 1) ^ ((krow & 7) << 4)));
          sf[0][nb] = MFMA_BF16(qf[0][ks], kf, sf[0][nb]);
          sf[1][nb] = MFMA_BF16(qf[1][ks], kf, sf[1][nb]);
        }
      }
      if (kv0 + 63 > q0w) {
#pragma unroll
        for (int mi = 0; mi < 2; ++mi)
#pragma unroll
          for (int nb = 0; nb < 4; ++nb)
#pragma unroll
            for (int r = 0; r < 4; ++r) {
              const int qq = q0w + mi * 16 + 4 * g + r;
              const int kk = kv0 + nb * 16 + l15;
              if (kk > qq) sf[mi][nb][r] = -__builtin_inff();
            }
      }
#pragma unroll
      for (int mi = 0; mi < 2; ++mi)
#pragma unroll
        for (int nb = 0; nb < 4; ++nb)
#pragma unroll
          for (int r = 0; r < 4; ++r) {
            const float p = exp2f(__builtin_fmaf(sf[mi][nb][r], SC, -4.0f));
            sf[mi][nb][r] = p;
            lsum[mi][r] += p;
          }
#pragma unroll
      for (int mi = 0; mi < 2; ++mi)
#pragma unroll
        for (int nb = 0; nb < 4; ++nb)
#pragma unroll
          for (int r = 0; r < 4; ++r)
            *(unsigned short*)(Ps + (mi * 16 + 4 * g + r) * 144 + ((nb * 16 + l15) << 1)) =
                bf16rn(sf[mi][nb][r]);
      asm volatile("s_waitcnt lgkmcnt(0)" ::: "memory");
#pragma unroll
      for (int mi = 0; mi < 2; ++mi)
#pragma unroll
        for (int ks = 0; ks < 2; ++ks) {
          bf16x8 pa = *(const bf16x8*)(Ps + (mi * 16 + l15) * 144 + ((ks * 32 + g * 8) << 1));
#pragma unroll
          for (int nb = 0; nb < 4; ++nb) {
            const int drow = nb * 16 + l15;
            bf16x8 vb = *(const bf16x8*)(Vs + drow * 128 +
                                         (((ks * 32 + g * 8) << 1) ^ ((drow & 7) << 4)));
            acc[mi][nb] = MFMA_BF16(pa, vb, acc[mi][nb]);
          }
        }
    }
#pragma unroll
    for (int mi = 0; mi < 2; ++mi)
#pragma unroll
      for (int r = 0; r < 4; ++r) {
        float s = lsum[mi][r];
        s += __shfl_xor(s, 1);
        s += __shfl_xor(s, 2);
        s += __shfl_xor(s, 4);
        s += __shfl_xor(s, 8);
        lsum[mi][r] = s;
      }
#pragma unroll
    for (int mi = 0; mi < 2; ++mi) {
      float inv[4];
#pragma unroll
      for (int r = 0; r < 4; ++r) inv[r] = 1.0f / lsum[mi][r];
#pragma unroll
      for (int nb = 0; nb < 4; ++nb)
#pragma unroll
        for (int r = 0; r < 4; ++r)
          ctx[(size_t)(b * 2048 + q0w + mi * 16 + 4 * g + r) * 1024 + h * 64 + nb * 16 + l15] =
              bf16rn(acc[mi][nb][r] * inv[r]);
    }
  }
}

extern "C" void kernel_launch(void* const* d_in, const int* in_sizes, int n_in,
                              void* d_out, int out_size, void* d_ws, size_t ws_size,
                              hipStream_t stream)
{
  const float* x   = (const float*)d_in[0];
  const float* l1s = (const float*)d_in[1];
  const float* l1b = (const float*)d_in[2];
  const float* l2s = (const float*)d_in[3];
  const float* l2b = (const float*)d_in[4];
  const float* Wq  = (const float*)d_in[5];
  const float* Wk  = (const float*)d_in[6];
  const float* Wv  = (const float*)d_in[7];
  const float* Wo  = (const float*)d_in[8];
  const float* bo  = (const float*)d_in[9];
  const float* Wfc = (const float*)d_in[10];
  const float* bfc = (const float*)d_in[11];
  const float* Wpj = (const float*)d_in[12];
  const float* bpj = (const float*)d_in[13];
  float* out = (float*)d_out;
  char* ws = (char*)d_ws;

  unsigned short* wT   = (unsigned short*)ws;                // 24MB weights
  unsigned short* wqkT = wT;                                 // [2048][1024] fused Q|K
  unsigned short* wvT  = wT + 2097152u;
  unsigned short* woT  = wT + 3145728u;
  unsigned short* wfcT = wT + 4194304u;
  unsigned short* wpjT = wT + 8388608u;
  unsigned short* ln1x = (unsigned short*)(ws + 25165824u);  // 16MB
  unsigned short* qkb  = (unsigned short*)(ws + 41943040u);  // 32MB [8192][2048]
  unsigned short* vTb  = (unsigned short*)(ws + 75497472u);  // 16MB
  unsigned short* ctx  = (unsigned short*)(ws + 92274688u);  // 16MB (reused as ln2x)
  unsigned short* ln2x = ctx;
  float* hbuf          = (float*)(ws + 109051904u);          // 32MB
  unsigned short* fcb  = (unsigned short*)(ws + 25165824u);  // 64MB, reuses ln1x..vTb

  convT_kernel<<<3072, 256, 0, stream>>>(Wq, Wk, Wv, Wo, Wfc, Wpj, wT);
  ln_kernel<<<8192, 256, 0, stream>>>(x, l1s, l1b, ln1x);
  g128<0><<<1024, 256, 65536, stream>>>(ln1x, wqkT, 2048, 1024,
                                        qkb, nullptr, nullptr, nullptr);
  gemm_bt<1><<<512, 256, 0, stream>>>(ln1x, wvT, 8192, 1024, 1024,
                                      vTb, nullptr, nullptr, nullptr);
  attn_kernel<<<dim3(64, 8), 256, 0, stream>>>(qkb, qkb + 1024, vTb, ctx);
  g128<2><<<512, 256, 65536, stream>>>(ctx, woT, 1024, 1024,
                                       nullptr, hbuf, bo, x);
  ln_kernel<<<8192, 256, 0, stream>>>(hbuf, l2s, l2b, ln2x);
  g128<3><<<2048, 256, 65536, stream>>>(ln2x, wfcT, 4096, 1024,
                                        fcb, nullptr, bfc, nullptr);
  g128<2><<<512, 256, 65536, stream>>>(fcb, wpjT, 1024, 4096,
                                       nullptr, out, bpj, hbuf);
}

// Round 15
// 364.645 us; speedup vs baseline: 1.2512x; 1.0426x over previous
//
#include <hip/hip_runtime.h>

typedef __attribute__((ext_vector_type(8))) short bf16x8;
typedef __attribute__((ext_vector_type(4))) float f32x4;

#define MFMA_BF16(a, b, c) __builtin_amdgcn_mfma_f32_16x16x32_bf16((a), (b), (c), 0, 0, 0)
#define VMCNT(N) asm volatile("s_waitcnt vmcnt(" #N ")" ::: "memory")
#define BAR() asm volatile("s_barrier" ::: "memory")

__device__ __forceinline__ unsigned short bf16rn(float f) {
  unsigned u = __builtin_bit_cast(unsigned, f);
  u += 0x7fffu + ((u >> 16) & 1u);
  return (unsigned short)(u >> 16);
}

__device__ __forceinline__ void gld_lds16(const void* g, void* l) {
  __builtin_amdgcn_global_load_lds((const __attribute__((address_space(1))) void*)g,
                                   (__attribute__((address_space(3))) void*)l, 16, 0, 0);
}

// ---------------- weight convert + transpose: W[K][N] f32 -> W^T[N][K] bf16 ----------------
__global__ __launch_bounds__(256) void convT_kernel(
    const float* __restrict__ wq, const float* __restrict__ wk,
    const float* __restrict__ wv, const float* __restrict__ wo,
    const float* __restrict__ wfc, const float* __restrict__ wpj,
    unsigned short* __restrict__ wsb)
{
  const int bid = blockIdx.x;
  const float* src; unsigned short* dst; int K, N, lb;
  if (bid < 1024) {
    const int m = bid >> 8; lb = bid & 255; K = 1024; N = 1024;
    src = (m == 0) ? wq : (m == 1) ? wk : (m == 2) ? wv : wo;
    dst = wsb + (size_t)m * 1048576u;
  } else if (bid < 2048) {
    lb = bid - 1024; K = 1024; N = 4096; src = wfc; dst = wsb + 4194304u;
  } else {
    lb = bid - 2048; K = 4096; N = 1024; src = wpj; dst = wsb + 8388608u;
  }
  const int tiles_k = K >> 6;
  const int tk = lb % tiles_k, tn = lb / tiles_k;
  const int k0 = tk << 6, n0 = tn << 6;
  const int t = threadIdx.x, kq = t & 15, nq = t >> 4;
  float4 r[4];
#pragma unroll
  for (int i = 0; i < 4; ++i)
    r[i] = *(const float4*)(src + (size_t)(k0 + kq * 4 + i) * N + n0 + nq * 4);
#pragma unroll
  for (int j = 0; j < 4; ++j) {
    ushort4 o;
    o.x = bf16rn(((const float*)&r[0])[j]);
    o.y = bf16rn(((const float*)&r[1])[j]);
    o.z = bf16rn(((const float*)&r[2])[j]);
    o.w = bf16rn(((const float*)&r[3])[j]);
    *(ushort4*)(dst + (size_t)(n0 + nq * 4 + j) * K + k0 + kq * 4) = o;
  }
}

// ---------------- layernorm: f32 [rows][1024] -> bf16 ----------------
__global__ __launch_bounds__(256) void ln_kernel(
    const float* __restrict__ x, const float* __restrict__ sc,
    const float* __restrict__ sh, unsigned short* __restrict__ out)
{
  const int row = blockIdx.x, t = threadIdx.x;
  const float4 v = *(const float4*)(x + (size_t)row * 1024 + t * 4);
  float s = v.x + v.y + v.z + v.w;
  float q = v.x * v.x + v.y * v.y + v.z * v.z + v.w * v.w;
#pragma unroll
  for (int off = 1; off < 64; off <<= 1) { s += __shfl_xor(s, off); q += __shfl_xor(q, off); }
  __shared__ float ps[4], pq[4];
  if ((t & 63) == 0) { ps[t >> 6] = s; pq[t >> 6] = q; }
  __syncthreads();
  s = ps[0] + ps[1] + ps[2] + ps[3];
  q = pq[0] + pq[1] + pq[2] + pq[3];
  const float mean = s * (1.f / 1024.f);
  const float var = q * (1.f / 1024.f) - mean * mean;
  const float inv = rsqrtf(var + 1e-5f);
  const float4 scv = *(const float4*)(sc + t * 4);
  const float4 shv = *(const float4*)(sh + t * 4);
  ushort4 o;
  o.x = bf16rn((v.x - mean) * inv * scv.x + shv.x);
  o.y = bf16rn((v.y - mean) * inv * scv.y + shv.y);
  o.z = bf16rn((v.z - mean) * inv * scv.z + shv.z);
  o.w = bf16rn((v.w - mean) * inv * scv.w + shv.w);
  *(ushort4*)(out + (size_t)row * 1024 + t * 4) = o;
}

// ---------------- 128x128 GEMM, kept only for V (EPI=1: transposed store) -----------------
template<int EPI>
__global__ __launch_bounds__(256) void gemm_bt(
    const unsigned short* __restrict__ A, const unsigned short* __restrict__ Bt,
    int M, int N, int K,
    unsigned short* __restrict__ outb, float* __restrict__ outf,
    const float* __restrict__ bias, const float* __restrict__ resid)
{
  __shared__ char smem[36864];
  const int t = threadIdx.x;
  const int lane = t & 63, w = t >> 6;
  const int g = lane >> 4, l15 = lane & 15;
  const int wr = w >> 1, wc = w & 1;
  const int bid = blockIdx.x;
  const int j = bid >> 3;
  const int tm = (bid & 7) * 8 + (j & 7);
  const int tn = j >> 3;
  const int m0 = tm * 128, n0 = tn * 128;

  f32x4 acc[4][4] = {};

  const int nkt = K >> 5;
  for (int kt = 0; kt < nkt; ++kt) {
    const int k0 = kt << 5;
    __syncthreads();
#pragma unroll
    for (int it = 0; it < 2; ++it) {
      const int c = it * 256 + t;
      const int row = c >> 2;
      const int ce = (c & 3) << 3;
      gld_lds16(A + (size_t)(m0 + row) * K + k0 + ce,
                smem + ((it * 256 + w * 64) << 4));
      gld_lds16(Bt + (size_t)(n0 + row) * K + k0 + ce,
                smem + 8192 + ((it * 256 + w * 64) << 4));
    }
    __syncthreads();
    bf16x8 a[4], b[4];
#pragma unroll
    for (int mi = 0; mi < 4; ++mi)
      a[mi] = *(const bf16x8*)(smem + (wr * 64 + mi * 16 + l15) * 64 + g * 16);
#pragma unroll
    for (int ni = 0; ni < 4; ++ni)
      b[ni] = *(const bf16x8*)(smem + 8192 + (wc * 64 + ni * 16 + l15) * 64 + g * 16);
#pragma unroll
    for (int mi = 0; mi < 4; ++mi)
#pragma unroll
      for (int ni = 0; ni < 4; ++ni)
        acc[mi][ni] = MFMA_BF16(a[mi], b[ni], acc[mi][ni]);
  }

  if constexpr (EPI == 1) {  // transposed store for V
    __syncthreads();
    unsigned short* T = (unsigned short*)(smem + w * 9216);  // [64 n][72 m-padded]
#pragma unroll
    for (int mi = 0; mi < 4; ++mi)
#pragma unroll
      for (int ni = 0; ni < 4; ++ni)
#pragma unroll
        for (int r = 0; r < 4; ++r)
          T[(ni * 16 + l15) * 72 + mi * 16 + 4 * g + r] = bf16rn(acc[mi][ni][r]);
    asm volatile("s_waitcnt lgkmcnt(0)" ::: "memory");
    const int bidx = m0 >> 11;
    const int srow = (m0 & 2047) + wr * 64 + ((lane & 7) << 3);
#pragma unroll
    for (int rr = 0; rr < 8; ++rr) {
      const int trow = rr * 8 + (lane >> 3);
      bf16x8 v = *(const bf16x8*)((char*)T + trow * 144 + ((lane & 7) << 4));
      *(bf16x8*)(outb + (size_t)(bidx * 1024 + n0 + wc * 64 + trow) * 2048 + srow) = v;
    }
  }
}

// ---------------- 128x128 BK=64 GEMM: 2 blocks/CU + quadrant phases + counted vmcnt ------
// 256 thr / 4 waves (2M x 2N; wave tile 64x64). LDS: 2 buf x (A[128][128B] + B[128][128B])
// = 64KB -> 2 INDEPENDENT blocks per CU (decoupled barrier groups - m114 overlap).
// 128B rows + slot'=slot^(row&7) involution on stage SOURCE and reads (0 conflicts).
// vmcnt ledger as R12 (proven): single VMCNT(6)/tile, never 0 mid-loop.
// EPI 0: bf16; 2: f32 = acc+bias+resid; 3: bf16 = gelu(acc+bias) [exp2-sigmoid form]
template<int EPI>
__global__ __launch_bounds__(256, 2) void g128(
    const unsigned short* __restrict__ A, const unsigned short* __restrict__ Bt,
    int N, int K,
    unsigned short* __restrict__ outb, float* __restrict__ outf,
    const float* __restrict__ bias, const float* __restrict__ resid)
{
  extern __shared__ char smem[];
  constexpr int BUFSZ = 32768;  // A 16KB + B 16KB
  const int t = threadIdx.x, lane = t & 63, w = t >> 6;
  const int g = lane >> 4, l15 = lane & 15;
  const int wr = w >> 1, wc = w & 1;  // 2M x 2N waves; wave tile 64 x 64
  const int bid = blockIdx.x;
  const int tm = (bid & 7) * 8 + ((bid >> 3) & 7);
  const int tn = bid >> 6;
  const int m0 = tm << 7, n0 = tn << 7;

  const int srow = t >> 3;
  const int colswz = (((t & 7) ^ (srow & 7)) << 3);
  const unsigned short* pA = A + (size_t)(m0 + srow) * K + colswz;
  const unsigned short* pB = Bt + (size_t)(n0 + srow) * K + colswz;
  const int ldw = w << 10;

  auto stA = [&](int TT, char* buf) {
#pragma unroll
    for (int i = 0; i < 4; ++i)
      gld_lds16(pA + TT * 64 + (size_t)(i * 32) * K, buf + i * 4096 + ldw);
  };
  auto stB02 = [&](int TT, char* buf) {
    gld_lds16(pB + TT * 64, buf + 16384 + ldw);
    gld_lds16(pB + TT * 64 + (size_t)64 * K, buf + 16384 + 8192 + ldw);
  };
  auto stB13 = [&](int TT, char* buf) {
    gld_lds16(pB + TT * 64 + (size_t)32 * K, buf + 16384 + 4096 + ldw);
    gld_lds16(pB + TT * 64 + (size_t)96 * K, buf + 16384 + 12288 + ldw);
  };

  const int sw0 = (((0 + g) ^ (l15 & 7)) << 4);
  const int sw1 = (((4 + g) ^ (l15 & 7)) << 4);
  const int NT = K >> 6;

  f32x4 acc[4][4] = {};
  bf16x8 av[4][2], bv0[2][2], bv1[2][2];

#define LDA_ALL(CB) { _Pragma("unroll") for (int mi = 0; mi < 4; ++mi) {                  \
    const int row_ = (wr * 64 + mi * 16 + l15) * 128;                                     \
    av[mi][0] = *(const bf16x8*)((CB) + row_ + sw0);                                      \
    av[mi][1] = *(const bf16x8*)((CB) + row_ + sw1); } }
#define LDB_H(CB, H, BV) { _Pragma("unroll") for (int ni = 0; ni < 2; ++ni) {             \
    const int row_ = 16384 + (wc * 64 + (H) * 32 + ni * 16 + l15) * 128;                  \
    BV[ni][0] = *(const bf16x8*)((CB) + row_ + sw0);                                      \
    BV[ni][1] = *(const bf16x8*)((CB) + row_ + sw1); } }
#define MMH(BV, H) { __builtin_amdgcn_s_setprio(1);                                       \
    _Pragma("unroll") for (int mi = 0; mi < 4; ++mi)                                      \
      _Pragma("unroll") for (int ni = 0; ni < 2; ++ni) {                                  \
        acc[mi][(H)*2+ni] = MFMA_BF16(av[mi][0], BV[ni][0], acc[mi][(H)*2+ni]);           \
        acc[mi][(H)*2+ni] = MFMA_BF16(av[mi][1], BV[ni][1], acc[mi][(H)*2+ni]);  }        \
    __builtin_amdgcn_s_setprio(0); }

  // prologue: full tile 0 (8 ops) + tile 1's A,B02 (6 ops); prove tile 0
  stA(0, smem); stB02(0, smem); stB13(0, smem);
  stA(1, smem + BUFSZ); stB02(1, smem + BUFSZ);
  VMCNT(6);
  BAR();

  for (int kt = 0; kt < NT; ++kt) {
    char* cb = smem + (kt & 1) * BUFSZ;
    char* ob = smem + ((kt & 1) ^ 1) * BUFSZ;
    LDA_ALL(cb);
    LDB_H(cb, 0, bv0);
    if (kt + 1 < NT) stB13(kt + 1, ob);
    BAR();
    MMH(bv0, 0);
    BAR();
    LDB_H(cb, 1, bv1);
    if (kt + 2 < NT) { stA(kt + 2, cb); stB02(kt + 2, cb); VMCNT(6); }
    else if (kt + 1 < NT) VMCNT(0);
    BAR();
    MMH(bv1, 1);
    BAR();
  }
#undef LDA_ALL
#undef LDB_H
#undef MMH

  if constexpr (EPI == 2) {
#pragma unroll
    for (int mi = 0; mi < 4; ++mi) {
      const int ro = mi * 16 + g * 4;
#pragma unroll
      for (int ci = 0; ci < 4; ++ci) {
        const int n = n0 + wc * 64 + ci * 16 + l15;
        const float bn = bias[n];
#pragma unroll
        for (int r = 0; r < 4; ++r) {
          const size_t m = m0 + wr * 64 + ro + r;
          outf[m * N + n] = acc[mi][ci][r] + bn + resid[m * N + n];
        }
      }
    }
  } else {
    __syncthreads();
    char* wsl = smem + w * 8192;  // per-wave bounce [64 rows][64 cols] bf16
#pragma unroll
    for (int mi = 0; mi < 4; ++mi) {
      const int ro = mi * 16 + g * 4;
#pragma unroll
      for (int ci = 0; ci < 4; ++ci) {
        const int co = ci * 16 + l15;
        float bn = 0.f;
        if constexpr (EPI == 3) bn = bias[n0 + wc * 64 + co];
#pragma unroll
        for (int r = 0; r < 4; ++r) {
          float v = acc[mi][ci][r];
          if constexpr (EPI == 3) {
            v += bn;
            // gelu(u) = u * sigmoid(1.5957691*(u+0.044715u^3))
            //         = u / (1 + exp2(-2.3022085*(u+0.044715u^3)))   [2c*log2e]
            const float inner = v + 0.044715f * v * v * v;
            const float s = exp2f(-2.3022085f * inner);
            v = v / (1.0f + s);
          }
          *(unsigned short*)(wsl + (ro + r) * 128 + co * 2) = bf16rn(v);
        }
      }
    }
#pragma unroll
    for (int s = 0; s < 8; ++s) {
      const int row = s * 8 + (lane >> 3);
      bf16x8 vv = *(const bf16x8*)(wsl + row * 128 + (lane & 7) * 16);
      *(bf16x8*)(outb + (size_t)(m0 + wr * 64 + row) * N + n0 + wc * 64 + (lane & 7) * 8) = vv;
    }
  }
}

// ---------------- flash attention, causal, D=64, QB=128 (4 waves x 32 rows), KB=64 --------
// R12-proven version. Q/K from fused QK buffer [8192][2048]: Q cols 0-1023, K cols 1024-2047.
__global__ __launch_bounds__(256) void attn_kernel(
    const unsigned short* __restrict__ qg, const unsigned short* __restrict__ kg,
    const unsigned short* __restrict__ vT, unsigned short* __restrict__ ctx)
{
  __shared__ char smem[34816];  // K 8KB | V_T 8KB | P 4x4608
  const int bh = blockIdx.x, b = bh >> 4, h = bh & 15;
  const int t = threadIdx.x, lane = t & 63, w = t >> 6, g = lane >> 4, l15 = lane & 15;
  char* Ks = smem;
  char* Vs = smem + 8192;
  char* Ps = smem + 16384 + w * 4608;

  const float SC = 0.18033688011112042f;  // 0.125 * log2(e)

  for (int pass = 0; pass < 2; ++pass) {
    const int qt = pass ? 15 - (int)blockIdx.y : (int)blockIdx.y;
    const int q0 = qt << 7;
    const int q0w = q0 + w * 32;

    bf16x8 qf[2][2];
#pragma unroll
    for (int mi = 0; mi < 2; ++mi)
#pragma unroll
      for (int ks = 0; ks < 2; ++ks)
        qf[mi][ks] = *(const bf16x8*)(qg + (size_t)(b * 2048 + q0w + mi * 16 + l15) * 2048 +
                                      h * 64 + ks * 32 + g * 8);

    f32x4 acc[2][4] = {};
    float lsum[2][4] = {};

    const int ntile = 2 * qt + 2;
    for (int kt = 0; kt < ntile; ++kt) {
      const int kv0 = kt << 6;
      __syncthreads();
#pragma unroll
      for (int it = 0; it < 2; ++it) {
        const int c = it * 256 + t;
        const int row = c >> 3;
        const int wb = (c & 7) << 4;
        const int sw = (wb ^ ((row & 7) << 4)) >> 1;
        gld_lds16(kg + (size_t)(b * 2048 + kv0 + row) * 2048 + h * 64 + sw,
                  Ks + ((it * 256 + w * 64) << 4));
        gld_lds16(vT + (size_t)(b * 1024 + h * 64 + row) * 2048 + kv0 + sw,
                  Vs + ((it * 256 + w * 64) << 4));
      }
      __syncthreads();

      f32x4 sf[2][4] = {};
#pragma unroll
      for (int nb = 0; nb < 4; ++nb) {
        const int krow = nb * 16 + l15;
#pragma unroll
        for (int ks = 0; ks < 2; ++ks) {
          bf16x8 kf = *(const bf16x8*)(Ks + krow * 128 +
                                       (((ks * 32 + g * 8) << 1) ^ ((krow & 7) << 4)));
          sf[0][nb] = MFMA_BF16(qf[0][ks], kf, sf[0][nb]);
          sf[1][nb] = MFMA_BF16(qf[1][ks], kf, sf[1][nb]);
        }
      }
      if (kv0 + 63 > q0w) {  // causal mask (wave-uniform branch)
#pragma unroll
        for (int mi = 0; mi < 2; ++mi)
#pragma unroll
          for (int nb = 0; nb < 4; ++nb)
#pragma unroll
            for (int r = 0; r < 4; ++r) {
              const int qq = q0w + mi * 16 + 4 * g + r;
              const int kk = kv0 + nb * 16 + l15;
              if (kk > qq) sf[mi][nb][r] = -__builtin_inff();
            }
      }
#pragma unroll
      for (int mi = 0; mi < 2; ++mi)
#pragma unroll
        for (int nb = 0; nb < 4; ++nb)
#pragma unroll
          for (int r = 0; r < 4; ++r) {
            const float p = exp2f(__builtin_fmaf(sf[mi][nb][r], SC, -4.0f));
            sf[mi][nb][r] = p;
            lsum[mi][r] += p;
          }
#pragma unroll
      for (int mi = 0; mi < 2; ++mi)
#pragma unroll
        for (int nb = 0; nb < 4; ++nb)
#pragma unroll
          for (int r = 0; r < 4; ++r)
            *(unsigned short*)(Ps + (mi * 16 + 4 * g + r) * 144 + ((nb * 16 + l15) << 1)) =
                bf16rn(sf[mi][nb][r]);
      asm volatile("s_waitcnt lgkmcnt(0)" ::: "memory");
#pragma unroll
      for (int mi = 0; mi < 2; ++mi)
#pragma unroll
        for (int ks = 0; ks < 2; ++ks) {
          bf16x8 pa = *(const bf16x8*)(Ps + (mi * 16 + l15) * 144 + ((ks * 32 + g * 8) << 1));
#pragma unroll
          for (int nb = 0; nb < 4; ++nb) {
            const int drow = nb * 16 + l15;
            bf16x8 vb = *(const bf16x8*)(Vs + drow * 128 +
                                         (((ks * 32 + g * 8) << 1) ^ ((drow & 7) << 4)));
            acc[mi][nb] = MFMA_BF16(pa, vb, acc[mi][nb]);
          }
        }
    }
#pragma unroll
    for (int mi = 0; mi < 2; ++mi)
#pragma unroll
      for (int r = 0; r < 4; ++r) {
        float s = lsum[mi][r];
        s += __shfl_xor(s, 1);
        s += __shfl_xor(s, 2);
        s += __shfl_xor(s, 4);
        s += __shfl_xor(s, 8);
        lsum[mi][r] = s;
      }
#pragma unroll
    for (int mi = 0; mi < 2; ++mi) {
      float inv[4];
#pragma unroll
      for (int r = 0; r < 4; ++r) inv[r] = 1.0f / lsum[mi][r];
#pragma unroll
      for (int nb = 0; nb < 4; ++nb)
#pragma unroll
        for (int r = 0; r < 4; ++r)
          ctx[(size_t)(b * 2048 + q0w + mi * 16 + 4 * g + r) * 1024 + h * 64 + nb * 16 + l15] =
              bf16rn(acc[mi][nb][r] * inv[r]);
    }
  }
}

extern "C" void kernel_launch(void* const* d_in, const int* in_sizes, int n_in,
                              void* d_out, int out_size, void* d_ws, size_t ws_size,
                              hipStream_t stream)
{
  const float* x   = (const float*)d_in[0];
  const float* l1s = (const float*)d_in[1];
  const float* l1b = (const float*)d_in[2];
  const float* l2s = (const float*)d_in[3];
  const float* l2b = (const float*)d_in[4];
  const float* Wq  = (const float*)d_in[5];
  const float* Wk  = (const float*)d_in[6];
  const float* Wv  = (const float*)d_in[7];
  const float* Wo  = (const float*)d_in[8];
  const float* bo  = (const float*)d_in[9];
  const float* Wfc = (const float*)d_in[10];
  const float* bfc = (const float*)d_in[11];
  const float* Wpj = (const float*)d_in[12];
  const float* bpj = (const float*)d_in[13];
  float* out = (float*)d_out;
  char* ws = (char*)d_ws;

  unsigned short* wT   = (unsigned short*)ws;                // 24MB weights
  unsigned short* wqkT = wT;                                 // [2048][1024] fused Q|K
  unsigned short* wvT  = wT + 2097152u;
  unsigned short* woT  = wT + 3145728u;
  unsigned short* wfcT = wT + 4194304u;
  unsigned short* wpjT = wT + 8388608u;
  unsigned short* ln1x = (unsigned short*)(ws + 25165824u);  // 16MB
  unsigned short* qkb  = (unsigned short*)(ws + 41943040u);  // 32MB [8192][2048]
  unsigned short* vTb  = (unsigned short*)(ws + 75497472u);  // 16MB
  unsigned short* ctx  = (unsigned short*)(ws + 92274688u);  // 16MB (reused as ln2x)
  unsigned short* ln2x = ctx;
  float* hbuf          = (float*)(ws + 109051904u);          // 32MB
  unsigned short* fcb  = (unsigned short*)(ws + 25165824u);  // 64MB, reuses ln1x..vTb

  convT_kernel<<<3072, 256, 0, stream>>>(Wq, Wk, Wv, Wo, Wfc, Wpj, wT);
  ln_kernel<<<8192, 256, 0, stream>>>(x, l1s, l1b, ln1x);
  g128<0><<<1024, 256, 65536, stream>>>(ln1x, wqkT, 2048, 1024,
                                        qkb, nullptr, nullptr, nullptr);
  gemm_bt<1><<<512, 256, 0, stream>>>(ln1x, wvT, 8192, 1024, 1024,
                                      vTb, nullptr, nullptr, nullptr);
  attn_kernel<<<dim3(64, 8), 256, 0, stream>>>(qkb, qkb + 1024, vTb, ctx);
  g128<2><<<512, 256, 65536, stream>>>(ctx, woT, 1024, 1024,
                                       nullptr, hbuf, bo, x);
  ln_kernel<<<8192, 256, 0, stream>>>(hbuf, l2s, l2b, ln2x);
  g128<3><<<2048, 256, 65536, stream>>>(ln2x, wfcT, 4096, 1024,
                                        fcb, nullptr, bfc, nullptr);
  g128<2><<<512, 256, 65536, stream>>>(fcb, wpjT, 1024, 4096,
                                       nullptr, out, bpj, hbuf);
}